// Round 5
// baseline (169.930 us; speedup 1.0000x reference)
//
#include <hip/hip_runtime.h>
#include <math.h>

// Problem constants (B=4, N=2048, C=81)
#define NPROP 2048
#define NIMG 4
#define NCLS 81
#define REGW 648          // C*8
#define SCORE_THRESH 0.05f
#define NMS_T 0.5f
#define DETS 100
#define XC 1023.0f        // IMG_W - 1
#define YC 799.0f         // IMG_H - 1
#define BBOX_CLIP 4.135166556742356f  // log(1000/16)
#define NBIN 4096         // 12-bit score-bin histogram
#define SEL 320           // target candidate count for tranche 1
#define MAXC 640          // LDS box-cache capacity (sorted positions)
#define SCAP 2112         // sidx capacity (proven max CbEnd)

struct SF {
  unsigned v32[NPROP];                   // flipped score bits (asc = desc score)
  unsigned short ci16[NPROP];            // argmax class per row
  unsigned short sidx[SCAP];             // sorted candidate -> row idx
  union {
    int hist[NBIN];                      // 16 KB (dead after threshold select)
    unsigned long long candk[NBIN / 2];  // tranche candidate keys (v32<<16|row)
  } u;
  int wsum[16];                          // per-wave scan partials
  float4 bxL[MAXC], bxR[MAXC];           // decoded boxes at sorted positions
  float  arL[MAXC], arR[MAXC];
  unsigned long long keepbL[34], keepbR[34];
  unsigned long long rowmL[64], rowmR[64];
  float4 cbL[64], cbR[64];               // chunk survivor boxes
  float  cbLa[64], cbRa[64];
  unsigned long long aL, aR;
  int cnt, prevCount, done, T, nvTot, ccL, ccR;
  unsigned kthV;
};                                        // ~62.7 KB

__device__ __forceinline__ float areaf(float4 v) {
  return fmaxf(v.z - v.x + 1.0f, 0.0f) * fmaxf(v.w - v.y + 1.0f, 0.0f);
}
__device__ __forceinline__ bool iou_gt(float4 a, float aa, float4 b, float ba) {
  float ix1 = fmaxf(a.x, b.x), iy1 = fmaxf(a.y, b.y);
  float ix2 = fminf(a.z, b.z), iy2 = fminf(a.w, b.w);
  float iw = fmaxf(ix2 - ix1 + 1.0f, 0.0f);
  float ih = fmaxf(iy2 - iy1 + 1.0f, 0.0f);
  float inter = iw * ih;
  return inter > NMS_T * fmaxf(aa + ba - inter, 1e-6f);
}
__device__ __forceinline__ float score_from_v(unsigned v) {
  unsigned uu = ~v;
  unsigned bits = (uu & 0x80000000u) ? (uu & 0x7fffffffu) : ~uu;
  return __uint_as_float(bits);
}
// maskrcnn BoxCoder.decode + clip for one side (isR: right regression slots)
__device__ __forceinline__ float4 decode_side(const float* __restrict__ reg,
                                              const float4* __restrict__ props,
                                              int grow, int ci, int isR) {
  const float* r = reg + (size_t)grow * REGW + ci * 8 + isR * 4;
  float4 P = props[grow];
  float w  = P.z - P.x + 1.0f;
  float h  = P.w - P.y + 1.0f;
  float cx = P.x + 0.5f * w;
  float cy = P.y + 0.5f * h;
  float dx = r[0] / 10.0f;
  float dy = r[1] / 10.0f;
  float dw = fminf(r[2] / 5.0f, BBOX_CLIP);
  float dh = fminf(r[3] / 5.0f, BBOX_CLIP);
  float pcx = dx * w + cx;
  float pcy = dy * h + cy;
  float pw = expf(dw) * w;
  float ph = expf(dh) * h;
  float4 o;
  o.x = fminf(fmaxf(pcx - 0.5f * pw, 0.0f), XC);
  o.y = fminf(fmaxf(pcy - 0.5f * ph, 0.0f), YC);
  o.z = fminf(fmaxf(pcx + 0.5f * pw - 1.0f, 0.0f), XC);
  o.w = fminf(fmaxf(pcy + 0.5f * ph - 1.0f, 0.0f), YC);
  return o;
}
__device__ __forceinline__ float4 get_sbox(SF* S, const float* reg,
                                           const float4* lp4, const float4* rp4,
                                           int b, int pos, int isR, bool lds) {
  if (lds) return isR ? S->bxR[pos] : S->bxL[pos];
  int row = S->sidx[pos];
  return decode_side(reg, isR ? rp4 : lp4, b * NPROP + row, S->ci16[row], isR);
}

// chunked dual greedy NMS over sorted positions [Cstart, CbEnd), early stop
// at 100 AND-survivors, direct output write.
__device__ void run_chunks(SF* S, const float* reg, const float4* lp4,
                           const float4* rp4, int b, float* ob,
                           int Cstart, int Cend, int CbEnd, bool lds) {
  int tid = threadIdx.x, ln = tid & 63, w = tid >> 6;
  for (int base = Cstart; base < CbEnd; base += 64) {
    // ---- ph1: 64x64 IoU bit matrices; waves 0-7 L, 8-15 R; rows via shfl ----
    {
      int isR = (w >= 8);
      float4 cbx = get_sbox(S, reg, lp4, rp4, b, base + ln, isR, lds);
      float car = lds ? (isR ? S->arR[base + ln] : S->arL[base + ln]) : areaf(cbx);
      int w8 = w & 7;
#pragma unroll
      for (int k = 0; k < 8; ++k) {
        int row = w8 * 8 + k;
        float4 rbx;
        rbx.x = __shfl(cbx.x, row); rbx.y = __shfl(cbx.y, row);
        rbx.z = __shfl(cbx.z, row); rbx.w = __shfl(cbx.w, row);
        float rar = __shfl(car, row);
        bool bit = (ln > row) && iou_gt(rbx, rar, cbx, car);
        unsigned long long bal = __ballot(bit);
        if (ln == 0) { if (isR) S->rowmR[row] = bal; else S->rowmL[row] = bal; }
      }
    }
    __syncthreads();
    // ---- ph2: branchless serial greedy per side (waves 0=L, 1=R) ----
    if (tid < 128) {
      int isR = (tid >= 64);
      unsigned long long* km = isR ? S->keepbR : S->keepbL;
      unsigned long long* rm = isR ? S->rowmR  : S->rowmL;
      unsigned long long a = km[base >> 6];
#pragma unroll
      for (int j = 0; j < 64; ++j)
        a &= ~((0ull - ((a >> j) & 1ull)) & rm[j]);
      if (ln == 0) {
        km[base >> 6] = a;
        if (isR) { S->aR = a; S->ccR = __popcll(a); }
        else     { S->aL = a; S->ccL = __popcll(a); }
      }
      if ((a >> ln) & 1ull) {          // compact survivors for ph3
        int pos = __popcll(a & ((1ull << ln) - 1ull));
        float4 v = get_sbox(S, reg, lp4, rp4, b, base + ln, isR, lds);
        if (isR) { S->cbR[pos] = v; S->cbRa[pos] = areaf(v); }
        else     { S->cbL[pos] = v; S->cbLa[pos] = areaf(v); }
      }
    }
    __syncthreads();
    // ---- ph2b (wave 0): AND-survivors -> rank, kth, output, stop check ----
    if (w == 0) {
      unsigned long long m = S->aL & S->aR;
      int before = S->prevCount;
      bool bit = (m >> ln) & 1ull;
      int rank = before + (int)__popcll(m & ((1ull << ln) - 1ull));
      int row = S->sidx[base + ln];
      unsigned vA = S->v32[row];
      unsigned long long selm = __ballot(bit && rank == DETS - 1);
      unsigned keffV = S->kthV;
      if (selm) keffV = __shfl(vA, __ffsll(selm) - 1);
      bool qual = bit && (rank < DETS || vA == keffV);  // top-100 or tie at kth
      if (qual) {
        float4 L = get_sbox(S, reg, lp4, rp4, b, base + ln, 0, lds);
        float4 R = get_sbox(S, reg, lp4, rp4, b, base + ln, 1, lds);
        float s = score_from_v(vA);
        float* orow = ob + row * 9;
        orow[0]=L.x; orow[1]=L.y; orow[2]=L.z; orow[3]=L.w;
        orow[4]=R.x; orow[5]=R.y; orow[6]=R.z; orow[7]=R.w;
        orow[8]=s;
      }
      if (ln == 0) {
        if (selm) S->kthV = keffV;
        int nc = before + (int)__popcll(m);
        S->prevCount = nc;
        if (nc >= DETS) {              // stop unless exact score-tie continues
          int nxt = base + 64;
          bool cont = false;
          if (nxt < Cend) cont = (S->v32[S->sidx[nxt]] == keffV);
          if (!cont) S->done = 1;
        }
      }
    } else {
      // ---- ph3 (waves 1-15): chunk survivors suppress later positions ----
      int cL = S->ccL, cR = S->ccR;
      if ((cL | cR) != 0) {
        for (int p = base + 64 + (tid - 64); p < CbEnd; p += 960) {
          float4 mbL = get_sbox(S, reg, lp4, rp4, b, p, 0, lds);
          float al = lds ? S->arL[p] : areaf(mbL);
          bool supL = false;
          for (int q = 0; q < cL; ++q)
            supL = supL || iou_gt(mbL, al, S->cbL[q], S->cbLa[q]);
          if (supL) atomicAnd(&S->keepbL[p >> 6], ~(1ull << (p & 63)));
          float4 mbR = get_sbox(S, reg, lp4, rp4, b, p, 1, lds);
          float ar_ = lds ? S->arR[p] : areaf(mbR);
          bool supR = false;
          for (int q = 0; q < cR; ++q)
            supR = supR || iou_gt(mbR, ar_, S->cbR[q], S->cbRa[q]);
          if (supR) atomicAnd(&S->keepbR[p >> 6], ~(1ull << (p & 63)));
        }
      }
    }
    __syncthreads();
    if (S->done) break;
  }
}

__global__ __launch_bounds__(1024) void fused_kernel(
    const float* __restrict__ logits, const float* __restrict__ reg,
    const float* __restrict__ lp, const float* __restrict__ rp,
    float* __restrict__ out) {
  __shared__ SF S;
  int b = blockIdx.x, tid = threadIdx.x, ln = tid & 63, w = tid >> 6;
  const float4* lp4 = (const float4*)lp;
  const float4* rp4 = (const float4*)rp;
  float* ob = out + (size_t)b * NPROP * 9;

  // zero this image's output
  float4* ob4 = (float4*)ob;
  float4 z4 = make_float4(0.f, 0.f, 0.f, 0.f);
  for (int i = tid; i < NPROP * 9 / 4; i += 1024) ob4[i] = z4;

  if (tid == 0) { S.cnt = 0; S.prevCount = 0; S.done = 0; S.T = NBIN - 1; S.kthV = 0u; }
  for (int i = tid; i < NBIN; i += 1024) S.u.hist[i] = 0;
  __syncthreads();

  // ---- phase A: softmax-argmax per row; 8 lanes/row, 128 rows/pass ----
  {
    int sub = tid & 7;
    int rbase = tid >> 3;
    for (int it = 0; it < 16; ++it) {
      int p = it * 128 + rbase;
      const float* g = logits + (size_t)(b * NPROP + p) * NCLS;
      float vals[10];
      float best = 0.f; int bi = 0;
#pragma unroll
      for (int k = 0; k < 10; ++k) {
        float x = g[sub + 8 * k];
        vals[k] = x;
        if (k == 0) { best = x; bi = sub; }
        else if (x > best) { best = x; bi = sub + 8 * k; }
      }
      float x80 = 0.0f;
      if (sub == 0) {
        x80 = g[80];
        if (x80 > best) { best = x80; bi = 80; }
      }
#pragma unroll
      for (int m = 1; m <= 4; m <<= 1) {   // 8-lane argmax, min-index ties
        float ov = __shfl_xor(best, m);
        int   oi = __shfl_xor(bi, m);
        if (ov > best || (ov == best && oi < bi)) { best = ov; bi = oi; }
      }
      float e = 0.0f;
#pragma unroll
      for (int k = 0; k < 10; ++k) e += expf(vals[k] - best);
      if (sub == 0) e += expf(x80 - best);
#pragma unroll
      for (int m = 1; m <= 4; m <<= 1) e += __shfl_xor(e, m);
      if (sub == 0) {
        float score = 1.0f / e;              // softmax at argmax (num = exp(0))
        bool vl = (bi >= 1) && (score > SCORE_THRESH);
        unsigned v = 0xFFFFFFFFu;
        if (vl) {
          unsigned uu = __float_as_uint(score);
          uu = (uu & 0x80000000u) ? ~uu : (uu | 0x80000000u);
          v = ~uu;
          atomicAdd(&S.u.hist[v >> 20], 1);
        }
        S.v32[p] = v;
        S.ci16[p] = (unsigned short)bi;
      }
    }
  }
  __syncthreads();

  // ---- phase B: shuffle-scan histogram -> threshold bin T, total nv ----
  {
    int t = tid;
    int b0 = S.u.hist[4*t], b1 = S.u.hist[4*t+1], b2 = S.u.hist[4*t+2], b3 = S.u.hist[4*t+3];
    int s1 = b0 + b1, s2 = s1 + b2, s3 = s2 + b3;
    int v = s3;
#pragma unroll
    for (int ofs = 1; ofs < 64; ofs <<= 1) {
      int n = __shfl_up(v, ofs);
      if (ln >= ofs) v += n;
    }
    if (ln == 63) S.wsum[w] = v;
    __syncthreads();
    if (t < 16) {
      int x = S.wsum[t];
#pragma unroll
      for (int ofs = 1; ofs < 16; ofs <<= 1) {
        int n = __shfl_up(x, ofs);
        if (t >= ofs) x += n;
      }
      S.wsum[t] = x;
    }
    __syncthreads();
    int incl = ((w > 0) ? S.wsum[w - 1] : 0) + v;
    int off = incl - s3;
    int c0 = off + b0, c1 = off + s1, c2 = off + s2, c3 = off + s3;
    if      (c0 >= SEL && off < SEL) S.T = 4*t;
    else if (c1 >= SEL && c0  < SEL) S.T = 4*t+1;
    else if (c2 >= SEL && c1  < SEL) S.T = 4*t+2;
    else if (c3 >= SEL && c2  < SEL) S.T = 4*t+3;
  }
  __syncthreads();
  int T = S.T, nvTot = S.wsum[15];

  int Cstart = 0, C1real = 0;
  bool t1lds = false;
  for (int tr = 0; tr < 2; ++tr) {
    if (tr == 1 && (S.done || C1real >= nvTot)) break;   // fallback not needed
    if (tid == 0) S.cnt = 0;
    __syncthreads();
    // ---- compact tranche candidates (keys into candk, hist is dead) ----
    for (int p = tid; p < NPROP; p += 1024) {
      unsigned v = S.v32[p];
      int bin = (int)(v >> 20);
      bool cand = (v != 0xFFFFFFFFu) && (tr == 0 ? (bin <= T) : (bin > T));
      unsigned long long mb = __ballot(cand);
      int lpos = (int)__popcll(mb & ((1ull << ln) - 1ull));
      int wb = 0;
      if (ln == 0 && mb) wb = atomicAdd(&S.cnt, (int)__popcll(mb));
      wb = __shfl(wb, 0);
      if (cand) S.u.candk[wb + lpos] = ((unsigned long long)v << 16) | (unsigned)p;
    }
    __syncthreads();
    int C2 = S.cnt;
    if (C2 == 0) { if (tr == 0) C1real = 0; continue; }
    int Cend = Cstart + C2;
    int CbEnd = Cstart + ((C2 + 63) & ~63);
    bool lds = (tr == 0) && (CbEnd <= MAXC);
    // ---- lockstep rank-sort: 1 barrier, broadcast LDS reads ----
    for (int i = tid; i < C2; i += 1024) {
      unsigned long long myk = S.u.candk[i];
      int rank = 0;
#pragma unroll 8
      for (int j = 0; j < C2; ++j)
        rank += (S.u.candk[j] < myk) ? 1 : 0;
      S.sidx[Cstart + rank] = (unsigned short)(myk & 0xFFFFull);
    }
    for (int i = Cend + tid; i < CbEnd; i += 1024) S.sidx[i] = 0;  // pads
    __syncthreads();
    // ---- decode candidate boxes into LDS (fast path) ----
    if (lds) {
      for (int i = Cstart + tid; i < CbEnd; i += 1024) {
        if (i < Cend) {
          int row = S.sidx[i];
          int grow = b * NPROP + row;
          int ci = S.ci16[row];
          float4 L = decode_side(reg, lp4, grow, ci, 0);
          float4 R = decode_side(reg, rp4, grow, ci, 1);
          S.bxL[i] = L; S.arL[i] = areaf(L);
          S.bxR[i] = R; S.arR[i] = areaf(R);
        } else {
          S.bxL[i] = z4; S.arL[i] = 1.0f;
          S.bxR[i] = z4; S.arR[i] = 1.0f;
        }
      }
    }
    // ---- init keep bits for this tranche's words ----
    for (int wd = (Cstart >> 6) + tid; wd < (CbEnd >> 6); wd += 1024) {
      int bb = wd << 6;
      unsigned long long mf = ~0ull;
      if (Cend < bb + 64) mf = (Cend > bb) ? ((1ull << (Cend - bb)) - 1ull) : 0ull;
      S.keepbL[wd] = mf; S.keepbR[wd] = mf;
    }
    __syncthreads();
    // ---- tranche 2 only: pre-suppress vs tranche-1 survivors ----
    if (tr == 1) {
      for (int p = Cstart + tid; p < Cend; p += 1024) {
        int row = S.sidx[p];
        int grow = b * NPROP + row;
        int ci = S.ci16[row];
        float4 mbL = decode_side(reg, lp4, grow, ci, 0); float al  = areaf(mbL);
        float4 mbR = decode_side(reg, rp4, grow, ci, 1); float ar_ = areaf(mbR);
        bool supL = false, supR = false;
        for (int q = 0; q < C1real; ++q) {
          if ((S.keepbL[q >> 6] >> (q & 63)) & 1ull) {
            float4 t4 = get_sbox(&S, reg, lp4, rp4, b, q, 0, t1lds);
            supL = supL || iou_gt(mbL, al, t4, areaf(t4));
          }
          if ((S.keepbR[q >> 6] >> (q & 63)) & 1ull) {
            float4 t4 = get_sbox(&S, reg, lp4, rp4, b, q, 1, t1lds);
            supR = supR || iou_gt(mbR, ar_, t4, areaf(t4));
          }
        }
        if (supL) atomicAnd(&S.keepbL[p >> 6], ~(1ull << (p & 63)));
        if (supR) atomicAnd(&S.keepbR[p >> 6], ~(1ull << (p & 63)));
      }
      __syncthreads();
    }
    run_chunks(&S, reg, lp4, rp4, b, ob, Cstart, Cend, CbEnd, lds);
    if (tr == 0) { C1real = Cend; t1lds = lds; Cstart = CbEnd; }
    __syncthreads();   // candk reuse ordering for tranche 2
  }
}

// ---------------------------------------------------------------------------
extern "C" void kernel_launch(void* const* d_in, const int* in_sizes, int n_in,
                              void* d_out, int out_size, void* d_ws, size_t ws_size,
                              hipStream_t stream) {
  const float* logits = (const float*)d_in[0];   // [8192, 81]
  const float* reg    = (const float*)d_in[1];   // [8192, 648]
  const float* lprop  = (const float*)d_in[2];   // [8192, 4]
  const float* rprop  = (const float*)d_in[3];   // [8192, 4]
  float* out = (float*)d_out;                    // [4, 2048, 9]
  (void)d_ws; (void)ws_size;

  fused_kernel<<<NIMG, 1024, 0, stream>>>(logits, reg, lprop, rprop, out);
}